// Round 1
// baseline (416.589 us; speedup 1.0000x reference)
//
#include <hip/hip_runtime.h>
#include <hip/hip_bf16.h>

typedef unsigned short ushort_t;
typedef unsigned int uint_t;
typedef __attribute__((ext_vector_type(4))) float f32x4;
typedef __attribute__((ext_vector_type(8))) short bf16x8;

#define B_DIM 512
#define IN_DIM 4096
#define OUT_DIM 4096
#define BM 128
#define BN 128
#define BK 32
#define KSPLIT 4

// ---------- helpers ----------
__device__ __forceinline__ ushort_t f2bf(float f) {
    union { float f; uint_t u; } v; v.f = f;
    uint_t r = v.u + 0x7fffu + ((v.u >> 16) & 1u);   // round-to-nearest-even
    return (ushort_t)(r >> 16);
}

__device__ __forceinline__ void async_copy16(void* lds, const void* g) {
    __builtin_amdgcn_global_load_lds(
        (const __attribute__((address_space(1))) uint_t*)g,
        (__attribute__((address_space(3))) uint_t*)lds, 16, 0, 0);
}

// ---------- kernel 1: W = (U @ t_hat) as bf16, row-major (OUT, IN) ----------
__global__ __launch_bounds__(256) void build_w(const float4* __restrict__ U4,
                                               const float* __restrict__ q,
                                               const int* __restrict__ expo,
                                               ushort_t* __restrict__ Wb) {
    const float scale = exp2f((float)expo[0]) * (1.0f / 7.0f);
    const float t0 = q[0] * scale, t1 = q[1] * scale,
                t2 = q[2] * scale, t3 = q[3] * scale;
    size_t i = ((size_t)blockIdx.x * 256 + threadIdx.x) * 8;  // 8 W elems/thread
    ushort_t r[8];
#pragma unroll
    for (int j = 0; j < 8; ++j) {
        float4 u = U4[i + j];                                  // 128B/lane contiguous
        float w = u.x * t0 + u.y * t1 + u.z * t2 + u.w * t3;
        r[j] = f2bf(w);
    }
    *(uint4*)(Wb + i) = *(const uint4*)r;                      // 16B/lane contiguous
}

// ---------- kernel 2: x -> bf16 ----------
__global__ __launch_bounds__(256) void conv_x(const float4* __restrict__ X4,
                                              ushort_t* __restrict__ Xb) {
    size_t i = ((size_t)blockIdx.x * 256 + threadIdx.x) * 8;  // elems
    float4 a = X4[i / 4], b = X4[i / 4 + 1];
    ushort_t r[8] = { f2bf(a.x), f2bf(a.y), f2bf(a.z), f2bf(a.w),
                      f2bf(b.x), f2bf(b.y), f2bf(b.z), f2bf(b.w) };
    *(uint4*)(Xb + i) = *(const uint4*)r;
}

// ---------- kernel 3: split-K GEMM, C_part[kz] = Xb @ Wb^T (both K-contig) ----
__global__ __launch_bounds__(256, 2) void gemm_splitk(
    const ushort_t* __restrict__ A,   // M x K bf16
    const ushort_t* __restrict__ Bm,  // N x K bf16
    float* __restrict__ part)         // KSPLIT x M x N fp32
{
    const int M = B_DIM, N = OUT_DIM, K = IN_DIM;
    __shared__ ushort_t sA[BM * BK];   // 8 KB
    __shared__ ushort_t sB[BN * BK];   // 8 KB

    const int tid  = threadIdx.x;
    const int lane = tid & 63;
    const int wave = tid >> 6;
    const int wr = (wave >> 1) * 64;   // wave row offset in tile
    const int wc = (wave & 1) * 64;    // wave col offset in tile

    const int m0 = blockIdx.y * BM;
    const int n0 = blockIdx.x * BN;
    const int kseg  = K / KSPLIT;                       // 1024
    const size_t kbase = (size_t)blockIdx.z * kseg;

    // staging: thread t loads 16B at row=t/4 (+64 on pass 1), kcol=(t%4)*8
    const int srow = tid >> 2;
    const int scol = (tid & 3) * 8;
    const ushort_t* ga0 = A  + (size_t)(m0 + srow) * K + kbase + scol;
    const ushort_t* ga1 = ga0 + (size_t)64 * K;
    const ushort_t* gb0 = Bm + (size_t)(n0 + srow) * K + kbase + scol;
    const ushort_t* gb1 = gb0 + (size_t)64 * K;
    ushort_t* la = sA + tid * 8;    // lds dst = wave-uniform base + lane*16B
    ushort_t* lb = sB + tid * 8;

    // fragment addressing: a-frag i at sA[(wr + i*16 + (lane&15))*BK + (lane>>4)*8]
    const int quad = lane >> 4;
    const int r16  = lane & 15;
    const ushort_t* fa = sA + (wr + r16) * BK + quad * 8;
    const ushort_t* fb = sB + (wc + r16) * BK + quad * 8;

    f32x4 acc[4][4] = {};

    const int nsteps = kseg / BK;                       // 32
    for (int s = 0; s < nsteps; ++s) {
        async_copy16(la,        ga0);
        async_copy16(la + 2048, ga1);
        async_copy16(lb,        gb0);
        async_copy16(lb + 2048, gb1);
        ga0 += BK; ga1 += BK; gb0 += BK; gb1 += BK;
        __syncthreads();   // compiler emits vmcnt(0) drain before barrier

        bf16x8 av[4], bv[4];
#pragma unroll
        for (int i = 0; i < 4; ++i) {
            av[i] = *(const bf16x8*)(fa + i * 16 * BK);
            bv[i] = *(const bf16x8*)(fb + i * 16 * BK);
        }
#pragma unroll
        for (int i = 0; i < 4; ++i)
#pragma unroll
            for (int j = 0; j < 4; ++j)
                acc[i][j] = __builtin_amdgcn_mfma_f32_16x16x32_bf16(
                    av[i], bv[j], acc[i][j], 0, 0, 0);
        __syncthreads();
    }

    // epilogue: C/D layout col=lane&15, row=quad*4+reg  [verified m89/m91]
    float* outp = part + (size_t)blockIdx.z * M * N;
#pragma unroll
    for (int i = 0; i < 4; ++i) {
        const int mrow = m0 + wr + i * 16 + quad * 4;
#pragma unroll
        for (int j = 0; j < 4; ++j) {
            const int ncol = n0 + wc + j * 16 + r16;
            float* o = outp + (size_t)mrow * N + ncol;
#pragma unroll
            for (int r = 0; r < 4; ++r)
                o[(size_t)r * N] = acc[i][j][r];
        }
    }
}

// ---------- kernel 4: out = sum_k part[k] + bias ----------
__global__ __launch_bounds__(256) void reduce_bias(const float4* __restrict__ part,
                                                   const float4* __restrict__ bias,
                                                   float4* __restrict__ out) {
    const int MN4 = (B_DIM * OUT_DIM) / 4;   // 524288
    int i = blockIdx.x * 256 + threadIdx.x;
    float4 s = part[i];
    float4 p1 = part[i + MN4];
    float4 p2 = part[i + 2 * MN4];
    float4 p3 = part[i + 3 * MN4];
    float4 bb = bias[i & 1023];              // OUT/4 = 1024
    float4 o;
    o.x = s.x + p1.x + p2.x + p3.x + bb.x;
    o.y = s.y + p1.y + p2.y + p3.y + bb.y;
    o.z = s.z + p1.z + p2.z + p3.z + bb.z;
    o.w = s.w + p1.w + p2.w + p3.w + bb.w;
    out[i] = o;
}

extern "C" void kernel_launch(void* const* d_in, const int* in_sizes, int n_in,
                              void* d_out, int out_size, void* d_ws, size_t ws_size,
                              hipStream_t stream) {
    const float* x    = (const float*)d_in[0];   // (512, 4096)
    const float* U    = (const float*)d_in[1];   // (4096*4096, 4)
    const float* q    = (const float*)d_in[2];   // (4,)
    const float* b    = (const float*)d_in[3];   // (4096,)
    const int*   expo = (const int*)d_in[4];     // scalar 0
    float* out = (float*)d_out;

    char* ws = (char*)d_ws;
    ushort_t* Wb  = (ushort_t*)ws;                       // 32 MB bf16 (OUT, IN)
    ushort_t* Xb  = (ushort_t*)(ws + 33554432);          // 4 MB bf16 (B, IN)
    float*    prt = (float*)(ws + 37748736);             // 32 MB fp32 partials

    // W reconstruction: 16.7M elems / 8 per thread = 2.09M threads
    build_w<<<8192, 256, 0, stream>>>((const float4*)U, q, expo, Wb);
    // x conversion: 2.09M elems / 8 = 262144 threads
    conv_x<<<1024, 256, 0, stream>>>((const float4*)x, Xb);
    // GEMM: grid (N/BN=32, M/BM=4, KSPLIT=4) = 512 blocks
    gemm_splitk<<<dim3(32, 4, 4), 256, 0, stream>>>(Xb, Wb, prt);
    // reduce: 2.09M elems / 4 = 524288 threads
    reduce_bias<<<2048, 256, 0, stream>>>((const float4*)prt, (const float4*)b,
                                          (float4*)out);
}

// Round 2
// 415.453 us; speedup vs baseline: 1.0027x; 1.0027x over previous
//
#include <hip/hip_runtime.h>
#include <hip/hip_bf16.h>

typedef unsigned short ushort_t;
typedef unsigned int uint_t;
typedef __attribute__((ext_vector_type(4))) float f32x4;
typedef __attribute__((ext_vector_type(8))) short bf16x8;

#define B_DIM 512
#define IN_DIM 4096
#define OUT_DIM 4096
#define BM 128
#define BN 128
#define BK 32
#define KSPLIT 8

// ---------- helpers ----------
__device__ __forceinline__ ushort_t f2bf(float f) {
    union { float f; uint_t u; } v; v.f = f;
    uint_t r = v.u + 0x7fffu + ((v.u >> 16) & 1u);   // round-to-nearest-even
    return (ushort_t)(r >> 16);
}

__device__ __forceinline__ void async_copy16(void* lds, const void* g) {
    __builtin_amdgcn_global_load_lds(
        (const __attribute__((address_space(1))) uint_t*)g,
        (__attribute__((address_space(3))) uint_t*)lds, 16, 0, 0);
}

// ---------- kernel 1: W = (U @ t_hat) as bf16, row-major (OUT, IN) ----------
// 1 element/thread: lane-contiguous float4 read (16B/lane), ushort write
// (2B/lane, 128B/wave). Fully coalesced both ways — fixes the 8x transaction
// over-issue of the round-0 version (128B-strided lanes -> 0.78 TB/s).
__global__ __launch_bounds__(256) void build_w(const float4* __restrict__ U4,
                                               const float* __restrict__ q,
                                               const int* __restrict__ expo,
                                               ushort_t* __restrict__ Wb) {
    const float scale = exp2f((float)expo[0]) * (1.0f / 7.0f);
    const float t0 = q[0] * scale, t1 = q[1] * scale,
                t2 = q[2] * scale, t3 = q[3] * scale;
    size_t i = (size_t)blockIdx.x * 256 + threadIdx.x;
    float4 u = U4[i];
    Wb[i] = f2bf(u.x * t0 + u.y * t1 + u.z * t2 + u.w * t3);
}

// ---------- kernel 2: x -> bf16 ----------
__global__ __launch_bounds__(256) void conv_x(const float4* __restrict__ X4,
                                              ushort_t* __restrict__ Xb) {
    size_t i = (size_t)blockIdx.x * 256 + threadIdx.x;   // one float4 per thread
    float4 a = X4[i];
    ushort_t r[4] = { f2bf(a.x), f2bf(a.y), f2bf(a.z), f2bf(a.w) };
    *(uint2*)(Xb + i * 4) = *(const uint2*)r;            // 8B/lane coalesced
}

// ---------- kernel 3: split-K GEMM, C_part[kz] = Xb @ Wb^T (both K-contig) ----
__global__ __launch_bounds__(256, 4) void gemm_splitk(
    const ushort_t* __restrict__ A,   // M x K bf16
    const ushort_t* __restrict__ Bm,  // N x K bf16
    float* __restrict__ part)         // KSPLIT x M x N fp32
{
    const int M = B_DIM, N = OUT_DIM, K = IN_DIM;
    __shared__ ushort_t sA[BM * BK];   // 8 KB
    __shared__ ushort_t sB[BN * BK];   // 8 KB

    const int tid  = threadIdx.x;
    const int lane = tid & 63;
    const int wave = tid >> 6;
    const int wr = (wave >> 1) * 64;   // wave row offset in tile
    const int wc = (wave & 1) * 64;    // wave col offset in tile

    const int m0 = blockIdx.y * BM;
    const int n0 = blockIdx.x * BN;
    const int kseg  = K / KSPLIT;                       // 512
    const size_t kbase = (size_t)blockIdx.z * kseg;

    // staging: thread t loads 16B at row=t/4 (+64 on pass 1), kcol=(t%4)*8
    const int srow = tid >> 2;
    const int scol = (tid & 3) * 8;
    const ushort_t* ga0 = A  + (size_t)(m0 + srow) * K + kbase + scol;
    const ushort_t* ga1 = ga0 + (size_t)64 * K;
    const ushort_t* gb0 = Bm + (size_t)(n0 + srow) * K + kbase + scol;
    const ushort_t* gb1 = gb0 + (size_t)64 * K;
    ushort_t* la = sA + tid * 8;    // lds dst = wave-uniform base + lane*16B
    ushort_t* lb = sB + tid * 8;

    // fragment addressing: a-frag i at sA[(wr + i*16 + (lane&15))*BK + (lane>>4)*8]
    const int quad = lane >> 4;
    const int r16  = lane & 15;
    const ushort_t* fa = sA + (wr + r16) * BK + quad * 8;
    const ushort_t* fb = sB + (wc + r16) * BK + quad * 8;

    f32x4 acc[4][4] = {};

    const int nsteps = kseg / BK;                       // 16
    for (int s = 0; s < nsteps; ++s) {
        async_copy16(la,        ga0);
        async_copy16(la + 2048, ga1);
        async_copy16(lb,        gb0);
        async_copy16(lb + 2048, gb1);
        ga0 += BK; ga1 += BK; gb0 += BK; gb1 += BK;
        __syncthreads();   // compiler emits vmcnt(0) drain before barrier

        bf16x8 av[4], bv[4];
#pragma unroll
        for (int i = 0; i < 4; ++i) {
            av[i] = *(const bf16x8*)(fa + i * 16 * BK);
            bv[i] = *(const bf16x8*)(fb + i * 16 * BK);
        }
#pragma unroll
        for (int i = 0; i < 4; ++i)
#pragma unroll
            for (int j = 0; j < 4; ++j)
                acc[i][j] = __builtin_amdgcn_mfma_f32_16x16x32_bf16(
                    av[i], bv[j], acc[i][j], 0, 0, 0);
        __syncthreads();
    }

    // epilogue: C/D layout col=lane&15, row=quad*4+reg  [verified m89/m91]
    float* outp = part + (size_t)blockIdx.z * M * N;
#pragma unroll
    for (int i = 0; i < 4; ++i) {
        const int mrow = m0 + wr + i * 16 + quad * 4;
#pragma unroll
        for (int j = 0; j < 4; ++j) {
            const int ncol = n0 + wc + j * 16 + r16;
            float* o = outp + (size_t)mrow * N + ncol;
#pragma unroll
            for (int r = 0; r < 4; ++r)
                o[(size_t)r * N] = acc[i][j][r];
        }
    }
}

// ---------- kernel 4: out = sum_k part[k] + bias ----------
__global__ __launch_bounds__(256) void reduce_bias(const float4* __restrict__ part,
                                                   const float4* __restrict__ bias,
                                                   float4* __restrict__ out) {
    const int MN4 = (B_DIM * OUT_DIM) / 4;   // 524288
    int i = blockIdx.x * 256 + threadIdx.x;
    float4 bb = bias[i & 1023];              // OUT/4 = 1024
    float sx = bb.x, sy = bb.y, sz = bb.z, sw = bb.w;
#pragma unroll
    for (int k = 0; k < KSPLIT; ++k) {
        float4 p = part[i + (size_t)k * MN4];
        sx += p.x; sy += p.y; sz += p.z; sw += p.w;
    }
    float4 o; o.x = sx; o.y = sy; o.z = sz; o.w = sw;
    out[i] = o;
}

extern "C" void kernel_launch(void* const* d_in, const int* in_sizes, int n_in,
                              void* d_out, int out_size, void* d_ws, size_t ws_size,
                              hipStream_t stream) {
    const float* x    = (const float*)d_in[0];   // (512, 4096)
    const float* U    = (const float*)d_in[1];   // (4096*4096, 4)
    const float* q    = (const float*)d_in[2];   // (4,)
    const float* b    = (const float*)d_in[3];   // (4096,)
    const int*   expo = (const int*)d_in[4];     // scalar 0
    float* out = (float*)d_out;

    char* ws = (char*)d_ws;
    ushort_t* Wb  = (ushort_t*)ws;                       // 32 MB bf16 (OUT, IN)
    ushort_t* Xb  = (ushort_t*)(ws + 33554432);          // 4 MB bf16 (B, IN)
    float*    prt = (float*)(ws + 37748736);             // 64 MB fp32 partials

    // W reconstruction: 16.7M elems, 1 per thread
    build_w<<<65536, 256, 0, stream>>>((const float4*)U, q, expo, Wb);
    // x conversion: 2.09M elems / 4 = 524288 threads
    conv_x<<<2048, 256, 0, stream>>>((const float4*)x, Xb);
    // GEMM: grid (N/BN=32, M/BM=4, KSPLIT=8) = 1024 blocks
    gemm_splitk<<<dim3(32, 4, KSPLIT), 256, 0, stream>>>(Xb, Wb, prt);
    // reduce: 2.09M elems / 4 = 524288 threads
    reduce_bias<<<2048, 256, 0, stream>>>((const float4*)prt, (const float4*)b,
                                          (float4*)out);
}